// Round 5
// baseline (3133.489 us; speedup 1.0000x reference)
//
#include <hip/hip_runtime.h>

#define B 4
#define N 8192
#define H 256
#define E 8192
#define M 2048
#define T_ITERS 8
#define ET 4

#define GR_COLS 16
#define GR_ROWG 1024
#define GR_PAD 264   // 256 + 8 bf16 pad -> row stride 528 B (2-way banks, free)

typedef __bf16 bf16x8 __attribute__((ext_vector_type(8)));
typedef float f32x4 __attribute__((ext_vector_type(4)));

__device__ __forceinline__ unsigned short f2bf(float x) {
    unsigned u = __float_as_uint(x);
    u += 0x7fffu + ((u >> 16) & 1u);
    return (unsigned short)(u >> 16);
}
__device__ __forceinline__ unsigned packsplit(float x) {
    unsigned hi = f2bf(x);
    float hif = __uint_as_float(hi << 16);
    unsigned lo = f2bf(x - hif);
    return (hi << 16) | lo;
}
__device__ __forceinline__ float unpacksplit(unsigned p) {
    return __uint_as_float(p & 0xffff0000u) + __uint_as_float(p << 16);
}
__device__ __forceinline__ float fsig(float x) { return 1.0f / (1.0f + __expf(-x)); }
__device__ __forceinline__ float ftanh(float x) {
    float cx = fminf(fmaxf(x, -30.0f), 30.0f);
    float t = __expf(2.0f * cx);
    return (t - 1.0f) / (t + 1.0f);
}

// fp32 -> split bf16 hi/lo pack (initial embedding only)
__global__ __launch_bounds__(256) void pack_kernel(
    const float* __restrict__ src, unsigned* __restrict__ dst)
{
    const int i = blockIdx.x * 256 + threadIdx.x;
    const float4 v = ((const float4*)src)[i];
    uint4 o = { packsplit(v.x), packsplit(v.y), packsplit(v.z), packsplit(v.w) };
    ((uint4*)dst)[i] = o;
}

// fp32 -> plain bf16 (weights)
__global__ __launch_bounds__(256) void wconv_kernel(
    const float* __restrict__ src, __bf16* __restrict__ dst)
{
    const int i = blockIdx.x * 256 + threadIdx.x;
    const float4 v = ((const float4*)src)[i];
    ushort4 o = { f2bf(v.x), f2bf(v.y), f2bf(v.z), f2bf(v.w) };
    ((ushort4*)dst)[i] = o;
}

// msg: for each edge, inc[tgt] += h[src] @ W_msg[e]^T + b_msg[e]
__global__ __launch_bounds__(256) void msgk(
    const unsigned* __restrict__ hpack,
    const int* __restrict__ ed0, const int* __restrict__ ed1,
    const int* __restrict__ ed2, const int* __restrict__ ed3,
    const __bf16* __restrict__ Wb, const float* __restrict__ b_msg,
    float* __restrict__ inc)
{
    const int tid = threadIdx.x;
    const int be = blockIdx.y;
    const int b = be >> 2, e = be & 3;
    const int* ed = (e == 0) ? ed0 : (e == 1) ? ed1 : (e == 2) ? ed2 : ed3;
    const int row0 = blockIdx.x * 64;

    __shared__ __bf16 sHi[64][136];
    __shared__ __bf16 sLo[64][136];
    __shared__ int s_tgt[64];

    if (tid < 64) s_tgt[tid] = ed[((size_t)b * E + row0 + tid) * 2 + 1];
    const int lrow = tid >> 2;
    const int c0 = (tid & 3) * 32;
    const int src = ed[((size_t)b * E + row0 + lrow) * 2];
    const unsigned* hrow = hpack + ((size_t)b * N + src) * H;

    const int wv = tid >> 6, ln = tid & 63, lq = ln >> 4, lm = ln & 15;
    const int jb = wv * 64;
    const __bf16* W0 = Wb + (size_t)e * H * H;

    f32x4 zero = {0.f, 0.f, 0.f, 0.f};
    f32x4 acc[4][4];
    #pragma unroll
    for (int mt = 0; mt < 4; ++mt)
        #pragma unroll
        for (int nt = 0; nt < 4; ++nt) acc[mt][nt] = zero;

    for (int ch = 0; ch < 2; ++ch) {
        __syncthreads();
        #pragma unroll
        for (int c = 0; c < 32; c += 4) {
            const uint4 u = *(const uint4*)(hrow + ch * 128 + c0 + c);
            ushort4 hi4 = { (unsigned short)(u.x >> 16), (unsigned short)(u.y >> 16),
                            (unsigned short)(u.z >> 16), (unsigned short)(u.w >> 16) };
            ushort4 lo4 = { (unsigned short)(u.x & 0xffffu), (unsigned short)(u.y & 0xffffu),
                            (unsigned short)(u.z & 0xffffu), (unsigned short)(u.w & 0xffffu) };
            *(ushort4*)&sHi[lrow][c0 + c] = hi4;
            *(ushort4*)&sLo[lrow][c0 + c] = lo4;
        }
        __syncthreads();
        #pragma unroll
        for (int ks = 0; ks < 4; ++ks) {
            const int kl = ks * 32 + lq * 8;
            const int kg = ch * 128 + kl;
            bf16x8 bfr[4];
            #pragma unroll
            for (int nt = 0; nt < 4; ++nt)
                bfr[nt] = *(const bf16x8*)(W0 + (size_t)(jb + nt * 16 + lm) * H + kg);
            #pragma unroll
            for (int mt = 0; mt < 4; ++mt) {
                const bf16x8 ahi = *(const bf16x8*)&sHi[mt * 16 + lm][kl];
                const bf16x8 alo = *(const bf16x8*)&sLo[mt * 16 + lm][kl];
                #pragma unroll
                for (int nt = 0; nt < 4; ++nt) {
                    acc[mt][nt] = __builtin_amdgcn_mfma_f32_16x16x32_bf16(ahi, bfr[nt], acc[mt][nt], 0, 0, 0);
                    acc[mt][nt] = __builtin_amdgcn_mfma_f32_16x16x32_bf16(alo, bfr[nt], acc[mt][nt], 0, 0, 0);
                }
            }
        }
    }

    float bias[4];
    #pragma unroll
    for (int nt = 0; nt < 4; ++nt) bias[nt] = b_msg[e * H + jb + nt * 16 + lm];
    float* incb = inc + (size_t)b * N * H;
    #pragma unroll
    for (int mt = 0; mt < 4; ++mt) {
        #pragma unroll
        for (int r = 0; r < 4; ++r) {
            const int tgt = s_tgt[mt * 16 + lq * 4 + r];
            float* dst = incb + (size_t)tgt * H;
            #pragma unroll
            for (int nt = 0; nt < 4; ++nt)
                atomicAdd(dst + jb + nt * 16 + lm, acc[mt][nt][r] + bias[nt]);
        }
    }
}

__device__ __forceinline__ void unpack8(uint4 a, uint4 b, bf16x8& hi, bf16x8& lo) {
    union U { unsigned u[4]; bf16x8 v; } uh, ul;
    uh.u[0] = (a.x >> 16) | (a.y & 0xffff0000u);
    uh.u[1] = (a.z >> 16) | (a.w & 0xffff0000u);
    uh.u[2] = (b.x >> 16) | (b.y & 0xffff0000u);
    uh.u[3] = (b.z >> 16) | (b.w & 0xffff0000u);
    ul.u[0] = (a.x & 0xffffu) | (a.y << 16);
    ul.u[1] = (a.z & 0xffffu) | (a.w << 16);
    ul.u[2] = (b.x & 0xffffu) | (b.y << 16);
    ul.u[3] = (b.z & 0xffffu) | (b.w << 16);
    hi = uh.v; lo = ul.v;
}

__device__ __forceinline__ void split8(const float4& a, const float4& b, bf16x8& hi, bf16x8& lo) {
    const float v[8] = {a.x, a.y, a.z, a.w, b.x, b.y, b.z, b.w};
    union U { unsigned short s[8]; bf16x8 v; } uh, ul;
    #pragma unroll
    for (int i = 0; i < 8; ++i) {
        const unsigned short h = f2bf(v[i]);
        uh.s[i] = h;
        ul.s[i] = f2bf(v[i] - __uint_as_float(((unsigned)h) << 16));
    }
    hi = uh.v; lo = ul.v;
}

// Fused GRU via MFMA, weight-stationary in LDS, XCD-pinned row-groups.
// bid decode puts all 16 col-group blocks of one row-group on ONE XCD
// (blockIdx % 8 == XCD empirically), so the row-group's 2 MB A-chunk is
// fetched into that XCD's L2 once and reused by the other 15 blocks.
__global__ __launch_bounds__(256, 3) void gruk(
    const float* __restrict__ inc, const unsigned* __restrict__ hpack,
    const __bf16* __restrict__ Wihb, const __bf16* __restrict__ Whhb,
    const float* __restrict__ b_ih, const float* __restrict__ b_hh,
    unsigned* __restrict__ hpack_new)
{
    __shared__ __bf16 sW[6 * GR_COLS * GR_PAD];  // 50688 B

    const int tid = threadIdx.x;
    const int bid = blockIdx.x;
    const int x = bid & 7;               // XCD (round-robin assumption)
    const int i5 = bid >> 3;             // 0..63
    const int rg = x + 8 * (i5 & 3);     // row-group 0..31, pinned to XCD rg%8
    const int cg = i5 >> 2;              // col-group 0..15
    const int c0 = cg * GR_COLS;
    const size_t row0 = (size_t)rg * GR_ROWG;

    // Stage weights once: 96 gate-rows (g*16+j) x 256 k.
    #pragma unroll
    for (int i = 0; i < 12; ++i) {
        const int f = tid + 256 * i;    // 0..3071
        const int row = f >> 5;         // 0..95
        const int kc = f & 31;          // uint4 (8 bf16) index
        const int g = row >> 4, j = row & 15;
        const __bf16* src = (g < 3)
            ? (Wihb + ((size_t)g * H + c0 + j) * H + kc * 8)
            : (Whhb + ((size_t)(g - 3) * H + c0 + j) * H + kc * 8);
        *(uint4*)(&sW[row * GR_PAD + kc * 8]) = *(const uint4*)src;
    }
    __syncthreads();

    const int wv = tid >> 6, ln = tid & 63, lq = ln >> 4, lm = ln & 15;

    float bi[3], bh[3];
    #pragma unroll
    for (int g = 0; g < 3; ++g) {
        bi[g] = b_ih[g * H + c0 + lm];
        bh[g] = b_hh[g * H + c0 + lm];
    }
    int ldsoff[6];
    #pragma unroll
    for (int g = 0; g < 6; ++g) ldsoff[g] = (g * 16 + lm) * GR_PAD + lq * 8;

    // prefetch regs
    float4 cx0[2], cx1[2]; uint4 cp0[2], cp1[2];
    float4 nx0[2], nx1[2]; uint4 np0[2], np1[2];

    // load A for (p=0, ks=0)
    {
        const size_t prow = row0 + wv * 32;
        #pragma unroll
        for (int mt = 0; mt < 2; ++mt) {
            const float*    xr = inc   + (prow + mt * 16 + lm) * H + lq * 8;
            const unsigned* hr = hpack + (prow + mt * 16 + lm) * H + lq * 8;
            cx0[mt] = *(const float4*)xr;       cx1[mt] = *(const float4*)(xr + 4);
            cp0[mt] = *(const uint4*)hr;        cp1[mt] = *(const uint4*)(hr + 4);
        }
    }

    for (int p = 0; p < 8; ++p) {
        const size_t prow = row0 + p * 128 + wv * 32;
        f32x4 zero = {0.f, 0.f, 0.f, 0.f};
        f32x4 acc[6][2];
        #pragma unroll
        for (int g = 0; g < 6; ++g) { acc[g][0] = zero; acc[g][1] = zero; }

        #pragma unroll
        for (int ks = 0; ks < 8; ++ks) {
            // prefetch next (p, ks) A
            const int last = (p == 7) && (ks == 7);
            if (!last) {
                const int nks = (ks == 7) ? 0 : ks + 1;
                const size_t nrow = (ks == 7) ? (prow + 128) : prow;
                #pragma unroll
                for (int mt = 0; mt < 2; ++mt) {
                    const float*    xr = inc   + (nrow + mt * 16 + lm) * H + nks * 32 + lq * 8;
                    const unsigned* hr = hpack + (nrow + mt * 16 + lm) * H + nks * 32 + lq * 8;
                    nx0[mt] = *(const float4*)xr;   nx1[mt] = *(const float4*)(xr + 4);
                    np0[mt] = *(const uint4*)hr;    np1[mt] = *(const uint4*)(hr + 4);
                }
            }
            bf16x8 xhi[2], xlo[2], hhi[2], hlo[2];
            #pragma unroll
            for (int mt = 0; mt < 2; ++mt) {
                split8(cx0[mt], cx1[mt], xhi[mt], xlo[mt]);
                unpack8(cp0[mt], cp1[mt], hhi[mt], hlo[mt]);
            }
            #pragma unroll
            for (int g = 0; g < 6; ++g) {
                const bf16x8 bf = *(const bf16x8*)&sW[ldsoff[g] + ks * 32];
                #pragma unroll
                for (int mt = 0; mt < 2; ++mt) {
                    const bf16x8 ahi = (g < 3) ? xhi[mt] : hhi[mt];
                    const bf16x8 alo = (g < 3) ? xlo[mt] : hlo[mt];
                    acc[g][mt] = __builtin_amdgcn_mfma_f32_16x16x32_bf16(ahi, bf, acc[g][mt], 0, 0, 0);
                    acc[g][mt] = __builtin_amdgcn_mfma_f32_16x16x32_bf16(alo, bf, acc[g][mt], 0, 0, 0);
                }
            }
            #pragma unroll
            for (int mt = 0; mt < 2; ++mt) {
                cx0[mt] = nx0[mt]; cx1[mt] = nx1[mt];
                cp0[mt] = np0[mt]; cp1[mt] = np1[mt];
            }
        }

        // epilogue for this pass
        const int col = c0 + lm;
        #pragma unroll
        for (int mt = 0; mt < 2; ++mt) {
            #pragma unroll
            for (int r = 0; r < 4; ++r) {
                const size_t row = prow + mt * 16 + lq * 4 + r;
                const float hold = unpacksplit(hpack[row * H + col]);
                const float rgt = fsig(acc[0][mt][r] + bi[0] + acc[3][mt][r] + bh[0]);
                const float zgt = fsig(acc[1][mt][r] + bi[1] + acc[4][mt][r] + bh[1]);
                const float ngt = ftanh(acc[2][mt][r] + bi[2] + rgt * (acc[5][mt][r] + bh[2]));
                const float o = (1.0f - zgt) * ngt + zgt * hold;
                hpack_new[row * H + col] = packsplit(o);
            }
        }
    }
}

// sel[b, m, :] = h[b, node_as_output[b, m], :]  (unpack split-bf16 -> fp32)
__global__ __launch_bounds__(256) void sel_kernel(
    const unsigned* __restrict__ hpack, const int* __restrict__ nao,
    float* __restrict__ out)
{
    const int row = blockIdx.x * 4 + (threadIdx.x >> 6);
    const int lane = threadIdx.x & 63;
    const int b = row >> 11;  // M = 2048
    const int idx = nao[row];
    const uint4 p = ((const uint4*)(hpack + ((size_t)b * N + idx) * H))[lane];
    float4 v = { unpacksplit(p.x), unpacksplit(p.y), unpacksplit(p.z), unpacksplit(p.w) };
    ((float4*)(out + (size_t)row * H))[lane] = v;
}

__global__ __launch_bounds__(256) void gmean_kernel(
    const float* __restrict__ sel, float* __restrict__ gacc)
{
    const int b = blockIdx.x >> 4;
    const int c = blockIdx.x & 15;
    const int j = threadIdx.x;
    float s = 0.0f;
    const float* base = sel + ((size_t)b * M + (size_t)c * 128) * H + j;
    for (int m = 0; m < 128; ++m) s += base[(size_t)m * H];
    atomicAdd(&gacc[b * H + j], s);
}

__global__ __launch_bounds__(256) void final_kernel(
    const float* __restrict__ gacc, float* __restrict__ out)
{
    const int i = blockIdx.x * 256 + threadIdx.x;
    const size_t sel_sz = (size_t)B * M * H;
    if (i < B * M) {
        out[sel_sz + i] = 1.0f;
    } else {
        const int j = i - B * M;
        out[sel_sz + B * M + j] = tanhf(gacc[j] * (1.0f / (float)M));
    }
}

extern "C" void kernel_launch(void* const* d_in, const int* in_sizes, int n_in,
                              void* d_out, int out_size, void* d_ws, size_t ws_size,
                              hipStream_t stream) {
    const float* emb  = (const float*)d_in[0];
    const int*   nao  = (const int*)d_in[2];
    const int*   ed0  = (const int*)d_in[3];
    const int*   ed1  = (const int*)d_in[4];
    const int*   ed2  = (const int*)d_in[5];
    const int*   ed3  = (const int*)d_in[6];
    const float* W_msg = (const float*)d_in[7];
    const float* b_msg = (const float*)d_in[8];
    const float* W_ih  = (const float*)d_in[9];
    const float* W_hh  = (const float*)d_in[10];
    const float* b_ih  = (const float*)d_in[11];
    const float* b_hh  = (const float*)d_in[12];
    float* out = (float*)d_out;

    const size_t helems = (size_t)B * N * H;      // 8.4M
    const size_t hbytes = helems * sizeof(unsigned);

    unsigned* hpA  = (unsigned*)d_ws;
    unsigned* hpB  = hpA + helems;
    float*    inc  = (float*)(hpB + helems);
    __bf16*   Wmb  = (__bf16*)((char*)inc + hbytes);
    __bf16*   Wihb = Wmb + (size_t)ET * H * H;
    __bf16*   Whhb = Wihb + (size_t)3 * H * H;
    float*    gacc = (float*)Wmb;                 // alias: used only after iters

    wconv_kernel<<<dim3(ET * H * H / 4 / 256), 256, 0, stream>>>(W_msg, Wmb);
    wconv_kernel<<<dim3(3 * H * H / 4 / 256), 256, 0, stream>>>(W_ih, Wihb);
    wconv_kernel<<<dim3(3 * H * H / 4 / 256), 256, 0, stream>>>(W_hh, Whhb);
    pack_kernel<<<dim3(helems / 4 / 256), 256, 0, stream>>>(emb, hpA);

    unsigned* cur = hpA;
    unsigned* nxt = hpB;
    for (int t = 0; t < T_ITERS; ++t) {
        hipMemsetAsync(inc, 0, hbytes, stream);
        msgk<<<dim3(E / 64, B * ET), 256, 0, stream>>>(
            cur, ed0, ed1, ed2, ed3, Wmb, b_msg, inc);
        gruk<<<dim3((16) * (B * N / GR_ROWG)), 256, 0, stream>>>(
            inc, cur, Wihb, Whhb, b_ih, b_hh, nxt);
        unsigned* tmp = cur; cur = nxt; nxt = tmp;
    }

    hipMemsetAsync(gacc, 0, (size_t)B * H * sizeof(float), stream);
    sel_kernel<<<dim3(B * M / 4), 256, 0, stream>>>(cur, nao, out);
    gmean_kernel<<<dim3(B * 16), 256, 0, stream>>>(out, gacc);
    final_kernel<<<dim3((B * M + B * H) / 256), 256, 0, stream>>>(gacc, out);
}

// Round 6
// 1982.136 us; speedup vs baseline: 1.5809x; 1.5809x over previous
//
#include <hip/hip_runtime.h>

#define B 4
#define N 8192
#define H 256
#define E 8192
#define M 2048
#define T_ITERS 8
#define ET 4

#define GK_ROWS 32

typedef __bf16 bf16x8 __attribute__((ext_vector_type(8)));
typedef float f32x4 __attribute__((ext_vector_type(4)));

__device__ __forceinline__ unsigned short f2bf(float x) {
    unsigned u = __float_as_uint(x);
    u += 0x7fffu + ((u >> 16) & 1u);
    return (unsigned short)(u >> 16);
}
__device__ __forceinline__ unsigned packsplit(float x) {
    unsigned hi = f2bf(x);
    float hif = __uint_as_float(hi << 16);
    unsigned lo = f2bf(x - hif);
    return (hi << 16) | lo;
}
__device__ __forceinline__ float unpacksplit(unsigned p) {
    return __uint_as_float(p & 0xffff0000u) + __uint_as_float(p << 16);
}
__device__ __forceinline__ float fsig(float x) { return 1.0f / (1.0f + __expf(-x)); }
__device__ __forceinline__ float ftanh(float x) {
    float cx = fminf(fmaxf(x, -30.0f), 30.0f);
    float t = __expf(2.0f * cx);
    return (t - 1.0f) / (t + 1.0f);
}

__global__ __launch_bounds__(256) void pack_kernel(
    const float* __restrict__ src, unsigned* __restrict__ dst)
{
    const int i = blockIdx.x * 256 + threadIdx.x;
    const float4 v = ((const float4*)src)[i];
    uint4 o = { packsplit(v.x), packsplit(v.y), packsplit(v.z), packsplit(v.w) };
    ((uint4*)dst)[i] = o;
}

// fp32 -> plain bf16 (msg weights, row-major)
__global__ __launch_bounds__(256) void wconv_kernel(
    const float* __restrict__ src, __bf16* __restrict__ dst)
{
    const int i = blockIdx.x * 256 + threadIdx.x;
    const float4 v = ((const float4*)src)[i];
    ushort4 o = { f2bf(v.x), f2bf(v.y), f2bf(v.z), f2bf(v.w) };
    ((ushort4*)dst)[i] = o;
}

// Gate weights -> fragment-major transposed layout:
// Wt[(((g*16 + c16)*8 + t)*64 + ln)*8 + i] = W[g][c16*16 + (ln&15)][t*32 + (ln>>4)*8 + i]
__global__ __launch_bounds__(256) void wtrans_kernel(
    const float* __restrict__ W_ih, const float* __restrict__ W_hh,
    __bf16* __restrict__ Wt)
{
    const int f = blockIdx.x * 256 + threadIdx.x;  // 0..49151
    const int ln = f & 63;
    const int t = (f >> 6) & 7;
    const int c16 = (f >> 9) & 15;
    const int g = f >> 13;
    const int col = c16 * 16 + (ln & 15);
    const int k = t * 32 + (ln >> 4) * 8;
    const float* src = (g < 3) ? (W_ih + ((size_t)g * H + col) * H + k)
                               : (W_hh + ((size_t)(g - 3) * H + col) * H + k);
    const float4 a = *(const float4*)src;
    const float4 b = *(const float4*)(src + 4);
    ushort4 o0 = { f2bf(a.x), f2bf(a.y), f2bf(a.z), f2bf(a.w) };
    ushort4 o1 = { f2bf(b.x), f2bf(b.y), f2bf(b.z), f2bf(b.w) };
    *(ushort4*)(Wt + (size_t)f * 8) = o0;
    *(ushort4*)(Wt + (size_t)f * 8 + 4) = o1;
}

__device__ __forceinline__ void unpack8(uint4 a, uint4 b, bf16x8& hi, bf16x8& lo) {
    union U { unsigned u[4]; bf16x8 v; } uh, ul;
    uh.u[0] = (a.x >> 16) | (a.y & 0xffff0000u);
    uh.u[1] = (a.z >> 16) | (a.w & 0xffff0000u);
    uh.u[2] = (b.x >> 16) | (b.y & 0xffff0000u);
    uh.u[3] = (b.z >> 16) | (b.w & 0xffff0000u);
    ul.u[0] = (a.x & 0xffffu) | (a.y << 16);
    ul.u[1] = (a.z & 0xffffu) | (a.w << 16);
    ul.u[2] = (b.x & 0xffffu) | (b.y << 16);
    ul.u[3] = (b.z & 0xffffu) | (b.w << 16);
    hi = uh.v; lo = ul.v;
}

__device__ __forceinline__ void split8(const float4& a, const float4& b, bf16x8& hi, bf16x8& lo) {
    const float v[8] = {a.x, a.y, a.z, a.w, b.x, b.y, b.z, b.w};
    union U { unsigned short s[8]; bf16x8 v; } uh, ul;
    #pragma unroll
    for (int i = 0; i < 8; ++i) {
        const unsigned short h = f2bf(v[i]);
        uh.s[i] = h;
        ul.s[i] = f2bf(v[i] - __uint_as_float(((unsigned)h) << 16));
    }
    hi = uh.v; lo = ul.v;
}

// msg: for each edge, inc[tgt] += h[src] @ W_msg[e]^T + b_msg[e]
__global__ __launch_bounds__(256) void msgk(
    const unsigned* __restrict__ hpack,
    const int* __restrict__ ed0, const int* __restrict__ ed1,
    const int* __restrict__ ed2, const int* __restrict__ ed3,
    const __bf16* __restrict__ Wb, const float* __restrict__ b_msg,
    float* __restrict__ inc)
{
    const int tid = threadIdx.x;
    const int be = blockIdx.y;
    const int b = be >> 2, e = be & 3;
    const int* ed = (e == 0) ? ed0 : (e == 1) ? ed1 : (e == 2) ? ed2 : ed3;
    const int row0 = blockIdx.x * 64;

    __shared__ __bf16 sHi[64][136];
    __shared__ __bf16 sLo[64][136];
    __shared__ int s_tgt[64];

    if (tid < 64) s_tgt[tid] = ed[((size_t)b * E + row0 + tid) * 2 + 1];
    const int lrow = tid >> 2;
    const int c0 = (tid & 3) * 32;
    const int src = ed[((size_t)b * E + row0 + lrow) * 2];
    const unsigned* hrow = hpack + ((size_t)b * N + src) * H;

    const int wv = tid >> 6, ln = tid & 63, lq = ln >> 4, lm = ln & 15;
    const int jb = wv * 64;
    const __bf16* W0 = Wb + (size_t)e * H * H;

    f32x4 zero = {0.f, 0.f, 0.f, 0.f};
    f32x4 acc[4][4];
    #pragma unroll
    for (int mt = 0; mt < 4; ++mt)
        #pragma unroll
        for (int nt = 0; nt < 4; ++nt) acc[mt][nt] = zero;

    for (int ch = 0; ch < 2; ++ch) {
        __syncthreads();
        #pragma unroll
        for (int c = 0; c < 32; c += 4) {
            const uint4 u = *(const uint4*)(hrow + ch * 128 + c0 + c);
            ushort4 hi4 = { (unsigned short)(u.x >> 16), (unsigned short)(u.y >> 16),
                            (unsigned short)(u.z >> 16), (unsigned short)(u.w >> 16) };
            ushort4 lo4 = { (unsigned short)(u.x & 0xffffu), (unsigned short)(u.y & 0xffffu),
                            (unsigned short)(u.z & 0xffffu), (unsigned short)(u.w & 0xffffu) };
            *(ushort4*)&sHi[lrow][c0 + c] = hi4;
            *(ushort4*)&sLo[lrow][c0 + c] = lo4;
        }
        __syncthreads();
        #pragma unroll
        for (int ks = 0; ks < 4; ++ks) {
            const int kl = ks * 32 + lq * 8;
            const int kg = ch * 128 + kl;
            bf16x8 bfr[4];
            #pragma unroll
            for (int nt = 0; nt < 4; ++nt)
                bfr[nt] = *(const bf16x8*)(W0 + (size_t)(jb + nt * 16 + lm) * H + kg);
            #pragma unroll
            for (int mt = 0; mt < 4; ++mt) {
                const bf16x8 ahi = *(const bf16x8*)&sHi[mt * 16 + lm][kl];
                const bf16x8 alo = *(const bf16x8*)&sLo[mt * 16 + lm][kl];
                #pragma unroll
                for (int nt = 0; nt < 4; ++nt) {
                    acc[mt][nt] = __builtin_amdgcn_mfma_f32_16x16x32_bf16(ahi, bfr[nt], acc[mt][nt], 0, 0, 0);
                    acc[mt][nt] = __builtin_amdgcn_mfma_f32_16x16x32_bf16(alo, bfr[nt], acc[mt][nt], 0, 0, 0);
                }
            }
        }
    }

    float bias[4];
    #pragma unroll
    for (int nt = 0; nt < 4; ++nt) bias[nt] = b_msg[e * H + jb + nt * 16 + lm];
    float* incb = inc + (size_t)b * N * H;
    #pragma unroll
    for (int mt = 0; mt < 4; ++mt) {
        #pragma unroll
        for (int r = 0; r < 4; ++r) {
            const int tgt = s_tgt[mt * 16 + lq * 4 + r];
            float* dst = incb + (size_t)tgt * H;
            #pragma unroll
            for (int nt = 0; nt < 4; ++nt)
                atomicAdd(dst + jb + nt * 16 + lm, acc[mt][nt][r] + bias[nt]);
        }
    }
}

// Fused GRU v3: block = 32 rows x 128 cols. A (xhi/xlo/hhi/hlo) staged once in
// LDS (64 KB, XOR-swizzled 16B chunks); gate weights streamed from L2 in
// fragment-major layout, double-buffered one k-step ahead.
__global__ __launch_bounds__(256, 2) void gruk(
    const float* __restrict__ inc, const unsigned* __restrict__ hpack,
    const __bf16* __restrict__ Wt,
    const float* __restrict__ b_ih, const float* __restrict__ b_hh,
    unsigned* __restrict__ hpack_new)
{
    __shared__ __bf16 sA[4 * GK_ROWS * 256];  // 65536 B; planes: xhi,xlo,hhi,hlo

    const int tid = threadIdx.x;
    const int bid = blockIdx.x;
    const int cb = bid & 1;            // column half: cols [128cb, 128cb+128)
    const int rblk = bid >> 1;
    const size_t row0 = (size_t)rblk * GK_ROWS;

    // ---- stage A: thread t -> row t>>3, 32 k starting at (t&7)*32 ----
    {
        const int r = tid >> 3;
        const int k0 = (tid & 7) * 32;
        const float* xr = inc + (row0 + r) * H + k0;
        const unsigned* hr = hpack + (row0 + r) * H + k0;
        #pragma unroll
        for (int c = 0; c < 4; ++c) {
            float4 xa = *(const float4*)(xr + c * 8);
            float4 xb = *(const float4*)(xr + c * 8 + 4);
            uint4 ha = *(const uint4*)(hr + c * 8);
            uint4 hb = *(const uint4*)(hr + c * 8 + 4);
            bf16x8 xhi, xlo, hhi, hlo;
            split8(xa, xb, xhi, xlo);
            unpack8(ha, hb, hhi, hlo);
            const int chunk = (k0 >> 3) + c;          // 0..31
            const int sc = chunk ^ (r & 7);           // bank swizzle
            __bf16* base = sA + r * 256 + sc * 8;
            *(bf16x8*)(base) = xhi;
            *(bf16x8*)(base + GK_ROWS * 256) = xlo;
            *(bf16x8*)(base + 2 * GK_ROWS * 256) = hhi;
            *(bf16x8*)(base + 3 * GK_ROWS * 256) = hlo;
        }
    }
    __syncthreads();

    const int wv = tid >> 6, ln = tid & 63, lq = ln >> 4, lm = ln & 15;
    const int c16a = cb * 8 + wv * 2;   // wave's two global col-tiles
    const int c16b = c16a + 1;

    f32x4 zero = {0.f, 0.f, 0.f, 0.f};
    f32x4 acc[6][2][2];  // [g][nt][mt]
    #pragma unroll
    for (int g = 0; g < 6; ++g)
        #pragma unroll
        for (int nt = 0; nt < 2; ++nt) { acc[g][nt][0] = zero; acc[g][nt][1] = zero; }

    const __bf16* wbase = Wt + ln * 8;

    bf16x8 Wc[6][2], Wn[6][2];
    #pragma unroll
    for (int g = 0; g < 6; ++g) {
        Wc[g][0] = *(const bf16x8*)(wbase + (size_t)((g * 16 + c16a) * 8) * 512);
        Wc[g][1] = *(const bf16x8*)(wbase + (size_t)((g * 16 + c16b) * 8) * 512);
    }

    #pragma unroll
    for (int ks = 0; ks < 8; ++ks) {
        if (ks < 7) {
            #pragma unroll
            for (int g = 0; g < 6; ++g) {
                Wn[g][0] = *(const bf16x8*)(wbase + (size_t)((g * 16 + c16a) * 8 + ks + 1) * 512);
                Wn[g][1] = *(const bf16x8*)(wbase + (size_t)((g * 16 + c16b) * 8 + ks + 1) * 512);
            }
        }
        // A fragments from LDS
        bf16x8 af[4][2];  // [plane][mt]
        #pragma unroll
        for (int mt = 0; mt < 2; ++mt) {
            const int r = mt * 16 + lm;
            const int sc = (ks * 4 + lq) ^ (r & 7);
            const __bf16* base = sA + r * 256 + sc * 8;
            af[0][mt] = *(const bf16x8*)(base);
            af[1][mt] = *(const bf16x8*)(base + GK_ROWS * 256);
            af[2][mt] = *(const bf16x8*)(base + 2 * GK_ROWS * 256);
            af[3][mt] = *(const bf16x8*)(base + 3 * GK_ROWS * 256);
        }
        #pragma unroll
        for (int g = 0; g < 6; ++g) {
            const int ph = (g < 3) ? 0 : 2;
            #pragma unroll
            for (int nt = 0; nt < 2; ++nt) {
                #pragma unroll
                for (int mt = 0; mt < 2; ++mt) {
                    acc[g][nt][mt] = __builtin_amdgcn_mfma_f32_16x16x32_bf16(af[ph][mt], Wc[g][nt], acc[g][nt][mt], 0, 0, 0);
                    acc[g][nt][mt] = __builtin_amdgcn_mfma_f32_16x16x32_bf16(af[ph + 1][mt], Wc[g][nt], acc[g][nt][mt], 0, 0, 0);
                }
            }
        }
        #pragma unroll
        for (int g = 0; g < 6; ++g) { Wc[g][0] = Wn[g][0]; Wc[g][1] = Wn[g][1]; }
    }

    // ---- fused gates + split-pack store ----
    const int colb = cb * 128 + wv * 32;
    #pragma unroll
    for (int nt = 0; nt < 2; ++nt) {
        const int col = colb + nt * 16 + lm;
        const float bi_r = b_ih[col], bi_z = b_ih[H + col], bi_n = b_ih[2 * H + col];
        const float bh_r = b_hh[col], bh_z = b_hh[H + col], bh_n = b_hh[2 * H + col];
        #pragma unroll
        for (int mt = 0; mt < 2; ++mt) {
            #pragma unroll
            for (int rr = 0; rr < 4; ++rr) {
                const size_t row = row0 + mt * 16 + lq * 4 + rr;
                const float hold = unpacksplit(hpack[row * H + col]);
                const float rg = fsig(acc[0][nt][mt][rr] + bi_r + acc[3][nt][mt][rr] + bh_r);
                const float zg = fsig(acc[1][nt][mt][rr] + bi_z + acc[4][nt][mt][rr] + bh_z);
                const float ng = ftanh(acc[2][nt][mt][rr] + bi_n + rg * (acc[5][nt][mt][rr] + bh_n));
                const float o = (1.0f - zg) * ng + zg * hold;
                hpack_new[row * H + col] = packsplit(o);
            }
        }
    }
}

__global__ __launch_bounds__(256) void sel_kernel(
    const unsigned* __restrict__ hpack, const int* __restrict__ nao,
    float* __restrict__ out)
{
    const int row = blockIdx.x * 4 + (threadIdx.x >> 6);
    const int lane = threadIdx.x & 63;
    const int b = row >> 11;  // M = 2048
    const int idx = nao[row];
    const uint4 p = ((const uint4*)(hpack + ((size_t)b * N + idx) * H))[lane];
    float4 v = { unpacksplit(p.x), unpacksplit(p.y), unpacksplit(p.z), unpacksplit(p.w) };
    ((float4*)(out + (size_t)row * H))[lane] = v;
}

__global__ __launch_bounds__(256) void gmean_kernel(
    const float* __restrict__ sel, float* __restrict__ gacc)
{
    const int b = blockIdx.x >> 4;
    const int c = blockIdx.x & 15;
    const int j = threadIdx.x;
    float s = 0.0f;
    const float* base = sel + ((size_t)b * M + (size_t)c * 128) * H + j;
    for (int m = 0; m < 128; ++m) s += base[(size_t)m * H];
    atomicAdd(&gacc[b * H + j], s);
}

__global__ __launch_bounds__(256) void final_kernel(
    const float* __restrict__ gacc, float* __restrict__ out)
{
    const int i = blockIdx.x * 256 + threadIdx.x;
    const size_t sel_sz = (size_t)B * M * H;
    if (i < B * M) {
        out[sel_sz + i] = 1.0f;
    } else {
        const int j = i - B * M;
        out[sel_sz + B * M + j] = tanhf(gacc[j] * (1.0f / (float)M));
    }
}

extern "C" void kernel_launch(void* const* d_in, const int* in_sizes, int n_in,
                              void* d_out, int out_size, void* d_ws, size_t ws_size,
                              hipStream_t stream) {
    const float* emb  = (const float*)d_in[0];
    const int*   nao  = (const int*)d_in[2];
    const int*   ed0  = (const int*)d_in[3];
    const int*   ed1  = (const int*)d_in[4];
    const int*   ed2  = (const int*)d_in[5];
    const int*   ed3  = (const int*)d_in[6];
    const float* W_msg = (const float*)d_in[7];
    const float* b_msg = (const float*)d_in[8];
    const float* W_ih  = (const float*)d_in[9];
    const float* W_hh  = (const float*)d_in[10];
    const float* b_ih  = (const float*)d_in[11];
    const float* b_hh  = (const float*)d_in[12];
    float* out = (float*)d_out;

    const size_t helems = (size_t)B * N * H;      // 8.4M
    const size_t hbytes = helems * sizeof(unsigned);

    unsigned* hpA  = (unsigned*)d_ws;
    unsigned* hpB  = hpA + helems;
    float*    inc  = (float*)(hpB + helems);
    __bf16*   Wmb  = (__bf16*)((char*)inc + hbytes);   // msg weights, row-major
    __bf16*   Wt   = Wmb + (size_t)ET * H * H;         // gate weights, frag-major
    float*    gacc = (float*)Wmb;                      // alias: used only after iters

    wconv_kernel<<<dim3(ET * H * H / 4 / 256), 256, 0, stream>>>(W_msg, Wmb);
    wtrans_kernel<<<dim3(6 * 16 * 8 * 64 / 256), 256, 0, stream>>>(W_ih, W_hh, Wt);
    pack_kernel<<<dim3(helems / 4 / 256), 256, 0, stream>>>(emb, hpA);

    unsigned* cur = hpA;
    unsigned* nxt = hpB;
    for (int t = 0; t < T_ITERS; ++t) {
        hipMemsetAsync(inc, 0, hbytes, stream);
        msgk<<<dim3(E / 64, B * ET), 256, 0, stream>>>(
            cur, ed0, ed1, ed2, ed3, Wmb, b_msg, inc);
        gruk<<<dim3(B * N / GK_ROWS * 2), 256, 0, stream>>>(
            inc, cur, Wt, b_ih, b_hh, nxt);
        unsigned* tmp = cur; cur = nxt; nxt = tmp;
    }

    hipMemsetAsync(gacc, 0, (size_t)B * H * sizeof(float), stream);
    sel_kernel<<<dim3(B * M / 4), 256, 0, stream>>>(cur, nao, out);
    gmean_kernel<<<dim3(B * 16), 256, 0, stream>>>(out, gacc);
    final_kernel<<<dim3((B * M + B * H) / 256), 256, 0, stream>>>(gacc, out);
}